// Round 1
// baseline (750.860 us; speedup 1.0000x reference)
//
#include <hip/hip_runtime.h>
#include <hip/hip_bf16.h>
#include <hip/hip_fp16.h>

#define HDIM 1024
#define BATCH 64
#define SEQ 2048
#define MTOT (BATCH*SEQ)   // 131072
#define BM 128
#define BN 128
#define BK 32

typedef float f32x4 __attribute__((ext_vector_type(4)));
typedef _Float16 half8 __attribute__((ext_vector_type(8)));

static __device__ __forceinline__ void gload_lds16(const void* g, void* l) {
  __builtin_amdgcn_global_load_lds((const __attribute__((address_space(1))) void*)g,
                                   (__attribute__((address_space(3))) void*)l, 16, 0, 0);
}

// ---------------- kernel 1: W1 [h][k] fp32 -> W1T [k][h] fp16 ----------------
__global__ void k_w1t(const float* __restrict__ W1, unsigned short* __restrict__ W1T) {
  __shared__ float tile[64][65];
  int h0 = blockIdx.x * 64, k0 = blockIdx.y * 64;
  int t = threadIdx.x;
#pragma unroll
  for (int j = 0; j < 4; ++j) {
    int q = j * 256 + t, r = q >> 4, c = (q & 15) * 4;
    float4 v = *(const float4*)(W1 + (size_t)(h0 + r) * HDIM + k0 + c);
    tile[r][c + 0] = v.x; tile[r][c + 1] = v.y; tile[r][c + 2] = v.z; tile[r][c + 3] = v.w;
  }
  __syncthreads();
#pragma unroll
  for (int j = 0; j < 4; ++j) {
    int q = j * 256 + t, r = q >> 4, c = (q & 15) * 4;  // out row k0+r, cols h0+c..
    union { _Float16 h[4]; ushort4 u; } cv;
    cv.h[0] = (_Float16)tile[c + 0][r];
    cv.h[1] = (_Float16)tile[c + 1][r];
    cv.h[2] = (_Float16)tile[c + 2][r];
    cv.h[3] = (_Float16)tile[c + 3][r];
    *(ushort4*)(W1T + (size_t)(k0 + r) * HDIM + h0 + c) = cv.u;
  }
}

// ---------------- kernel 2: dec_proj = dh @ W2 + b  (fp32) ----------------
__global__ void k_decproj(const float* __restrict__ dh, const float* __restrict__ W2,
                          const float* __restrict__ W2b, float* __restrict__ dp) {
  __shared__ float drow[HDIM];
  int b = blockIdx.x, t = threadIdx.x;
#pragma unroll
  for (int j = 0; j < 4; ++j) drow[j * 256 + t] = dh[(size_t)b * HDIM + j * 256 + t];
  __syncthreads();
  f32x4 acc = {0.f, 0.f, 0.f, 0.f};
#pragma unroll 16
  for (int h = 0; h < HDIM; ++h) {
    float d = drow[h];
    f32x4 w = *(const f32x4*)(W2 + (size_t)h * HDIM + t * 4);
    acc += w * d;
  }
  acc += *(const f32x4*)(W2b + t * 4);
  *(f32x4*)(dp + (size_t)b * HDIM + t * 4) = acc;
}

// ---------------- kernel 3: main fused GEMM + tanh + v-dot -> score partials ----------------
__global__ __launch_bounds__(256, 2) void k_scores(
    const float* __restrict__ E, const unsigned short* __restrict__ W1T,
    const float* __restrict__ W1b, const float* __restrict__ dp,
    const float* __restrict__ vw, float* __restrict__ spart) {
  __shared__ unsigned short As[BM * BK];   // [row][k] fp16
  __shared__ unsigned short Bs[BN * BK];   // [col][k] fp16 (B^T)
  __shared__ float biasv[BN], vv[BN];
  __shared__ float scr[BM][2];

  int t = threadIdx.x;
  int bid = blockIdx.x;
  int nt = bid & 7, mt = bid >> 3;
  int m0 = mt * BM, n0 = nt * BN;
  int b = m0 >> 11;   // 2048 rows per batch

  if (t < BN) {
    int k = n0 + t;
    biasv[t] = W1b[k] + dp[(size_t)b * HDIM + k];
    vv[t] = vw[k];
  }

  int lane = t & 63, wid = t >> 6;
  int wr = wid >> 1, wc = wid & 1;
  int l15 = lane & 15, l4 = lane >> 4;

  f32x4 acc[4][4];
#pragma unroll
  for (int i = 0; i < 4; ++i)
#pragma unroll
    for (int j = 0; j < 4; ++j) acc[i][j] = {0.f, 0.f, 0.f, 0.f};

  const float* Abase = E + (size_t)m0 * HDIM;

  for (int kt = 0; kt < HDIM / BK; ++kt) {
    // stage A: fp32 -> fp16, reg path
#pragma unroll
    for (int j = 0; j < 4; ++j) {
      int q = j * 256 + t;
      int r = q >> 3, c = (q & 7) * 4;
      float4 v = *(const float4*)(Abase + (size_t)r * HDIM + kt * BK + c);
      union { _Float16 h[4]; unsigned long long u; } cv;
      cv.h[0] = (_Float16)v.x; cv.h[1] = (_Float16)v.y;
      cv.h[2] = (_Float16)v.z; cv.h[3] = (_Float16)v.w;
      *(unsigned long long*)&As[q * 4] = cv.u;
    }
    // stage B: fp16 direct global->LDS (linear dest, per-lane src)
#pragma unroll
    for (int j = 0; j < 2; ++j) {
      int off = (wid * 2 + j) * 1024 + lane * 16;  // byte offset in Bs
      int row = off >> 6;                           // n index
      int kk = (off & 63) >> 1;                     // k element
      const unsigned short* g = W1T + (size_t)(n0 + row) * HDIM + kt * BK + kk;
      gload_lds16(g, (char*)Bs + (size_t)(wid * 2 + j) * 1024);
    }
    __syncthreads();

    half8 af[4], bf[4];
#pragma unroll
    for (int mi = 0; mi < 4; ++mi)
      af[mi] = *(const half8*)&As[(wr * 64 + mi * 16 + l15) * BK + l4 * 8];
#pragma unroll
    for (int ni = 0; ni < 4; ++ni)
      bf[ni] = *(const half8*)&Bs[(wc * 64 + ni * 16 + l15) * BK + l4 * 8];
#pragma unroll
    for (int mi = 0; mi < 4; ++mi)
#pragma unroll
      for (int ni = 0; ni < 4; ++ni)
        acc[mi][ni] = __builtin_amdgcn_mfma_f32_16x16x32_f16(af[mi], bf[ni], acc[mi][ni], 0, 0, 0);
    __syncthreads();
  }

  // epilogue: bias + tanh + v-dot, reduce 16 cols/lane-group, then across wc via LDS
  float bias_l[4], v_l[4];
#pragma unroll
  for (int ni = 0; ni < 4; ++ni) {
    bias_l[ni] = biasv[wc * 64 + ni * 16 + l15];
    v_l[ni] = vv[wc * 64 + ni * 16 + l15];
  }
#pragma unroll
  for (int mi = 0; mi < 4; ++mi) {
#pragma unroll
    for (int r = 0; r < 4; ++r) {
      float s = 0.f;
#pragma unroll
      for (int ni = 0; ni < 4; ++ni) {
        float x = acc[mi][ni][r] + bias_l[ni];
        float ex = __expf(2.f * x);
        float th = 1.f - 2.f / (ex + 1.f);   // tanh(x), saturates correctly at +-1
        s += th * v_l[ni];
      }
      s += __shfl_xor(s, 1); s += __shfl_xor(s, 2);
      s += __shfl_xor(s, 4); s += __shfl_xor(s, 8);
      if (l15 == 0) scr[wr * 64 + mi * 16 + l4 * 4 + r][wc] = s;
    }
  }
  __syncthreads();
  if (t < BM) spart[((size_t)m0 + t) * 8 + nt] = scr[t][0] + scr[t][1];
}

// ---------------- kernel 4: softmax over S per batch ----------------
__global__ void k_softmax(const float* __restrict__ spart, float* __restrict__ attn) {
  __shared__ float sc[SEQ];
  __shared__ float red[8];
  int b = blockIdx.x, t = threadIdx.x;
  float mx = -1e30f;
#pragma unroll
  for (int j = 0; j < 8; ++j) {
    int s = j * 256 + t;
    const f32x4* p = (const f32x4*)(spart + ((size_t)b * SEQ + s) * 8);
    f32x4 x = p[0], y = p[1];
    float v = (x[0] + x[1]) + (x[2] + x[3]) + (y[0] + y[1]) + (y[2] + y[3]);
    sc[s] = v;
    mx = fmaxf(mx, v);
  }
  for (int m = 1; m < 64; m <<= 1) mx = fmaxf(mx, __shfl_xor(mx, m));
  if ((t & 63) == 0) red[t >> 6] = mx;
  __syncthreads();
  mx = fmaxf(fmaxf(red[0], red[1]), fmaxf(red[2], red[3]));
  float w[8]; float sum = 0.f;
#pragma unroll
  for (int j = 0; j < 8; ++j) {
    float e = __expf(sc[j * 256 + t] - mx);
    w[j] = e; sum += e;
  }
  for (int m = 1; m < 64; m <<= 1) sum += __shfl_xor(sum, m);
  if ((t & 63) == 0) red[4 + (t >> 6)] = sum;
  __syncthreads();
  float inv = 1.f / (red[4] + red[5] + red[6] + red[7]);
#pragma unroll
  for (int j = 0; j < 8; ++j)
    attn[(size_t)b * SEQ + j * 256 + t] = w[j] * inv;
}

// ---------------- kernel 5: context partials over s-chunks ----------------
__global__ void k_ctx_part(const float* __restrict__ E, const float* __restrict__ attn,
                           float* __restrict__ cpart) {
  int b = blockIdx.x >> 4, ch = blockIdx.x & 15;
  int t = threadIdx.x;
  const float* wrow = attn + (size_t)b * SEQ + ch * 128;
  const float* Eb = E + ((size_t)b * SEQ + ch * 128) * HDIM;
  f32x4 acc = {0.f, 0.f, 0.f, 0.f};
#pragma unroll 4
  for (int s = 0; s < 128; ++s) {
    float w = wrow[s];
    f32x4 e = *(const f32x4*)(Eb + (size_t)s * HDIM + t * 4);
    acc += e * w;
  }
  *(f32x4*)(cpart + (size_t)blockIdx.x * HDIM + t * 4) = acc;
}

// ---------------- kernel 6: reduce context partials ----------------
__global__ void k_ctx_reduce(const float* __restrict__ cpart, float* __restrict__ ctx) {
  int idx = blockIdx.x * 256 + threadIdx.x;  // 0..65535
  int b = idx >> 10, k = idx & 1023;
  float s = 0.f;
#pragma unroll
  for (int c = 0; c < 16; ++c) s += cpart[((size_t)(b * 16 + c)) * HDIM + k];
  ctx[idx] = s;
}

extern "C" void kernel_launch(void* const* d_in, const int* in_sizes, int n_in,
                              void* d_out, int out_size, void* d_ws, size_t ws_size,
                              hipStream_t stream) {
  const float* dh  = (const float*)d_in[0];
  const float* E   = (const float*)d_in[1];
  const float* W1w = (const float*)d_in[2];
  const float* W1b = (const float*)d_in[3];
  const float* W2w = (const float*)d_in[4];
  const float* W2b = (const float*)d_in[5];
  const float* vw  = (const float*)d_in[6];
  float* out  = (float*)d_out;
  float* ctx  = out;            // [64,1024]
  float* attn = out + BATCH * HDIM;  // [64,2048]

  char* ws = (char*)d_ws;
  unsigned short* W1T = (unsigned short*)ws;                       // 2 MB
  float* dp    = (float*)(ws + (2u << 20));                        // 256 KB
  float* spart = (float*)(ws + (2u << 20) + (256u << 10));         // 4 MB
  float* cpart = (float*)(ws + (6u << 20) + (256u << 10));         // 4 MB
  // total ws use: 10.25 MB

  k_w1t<<<dim3(16, 16), 256, 0, stream>>>(W1w, W1T);
  k_decproj<<<BATCH, 256, 0, stream>>>(dh, W2w, W2b, dp);
  k_scores<<<(MTOT / BM) * (HDIM / BN), 256, 0, stream>>>(E, W1T, W1b, dp, vw, spart);
  k_softmax<<<BATCH, 256, 0, stream>>>(spart, attn);
  k_ctx_part<<<BATCH * 16, 256, 0, stream>>>(E, attn, cpart);
  k_ctx_reduce<<<256, 256, 0, stream>>>(cpart, ctx);
}

// Round 2
// 592.445 us; speedup vs baseline: 1.2674x; 1.2674x over previous
//
#include <hip/hip_runtime.h>
#include <hip/hip_bf16.h>
#include <hip/hip_fp16.h>

#define HDIM 1024
#define BATCH 64
#define SEQ 2048
#define MTOT (BATCH*SEQ)   // 131072
#define BM 128
#define BN 128
#define BK 32

typedef float f32x4 __attribute__((ext_vector_type(4)));
typedef _Float16 half8 __attribute__((ext_vector_type(8)));

static __device__ __forceinline__ void gload_lds16(const void* g, void* l) {
  __builtin_amdgcn_global_load_lds((const __attribute__((address_space(1))) void*)g,
                                   (__attribute__((address_space(3))) void*)l, 16, 0, 0);
}

// ---------------- kernel 1: W1 [h][k] fp32 -> W1T [k][h] fp16 ----------------
__global__ void k_w1t(const float* __restrict__ W1, unsigned short* __restrict__ W1T) {
  __shared__ float tile[64][65];
  int h0 = blockIdx.x * 64, k0 = blockIdx.y * 64;
  int t = threadIdx.x;
#pragma unroll
  for (int j = 0; j < 4; ++j) {
    int q = j * 256 + t, r = q >> 4, c = (q & 15) * 4;
    float4 v = *(const float4*)(W1 + (size_t)(h0 + r) * HDIM + k0 + c);
    tile[r][c + 0] = v.x; tile[r][c + 1] = v.y; tile[r][c + 2] = v.z; tile[r][c + 3] = v.w;
  }
  __syncthreads();
#pragma unroll
  for (int j = 0; j < 4; ++j) {
    int q = j * 256 + t, r = q >> 4, c = (q & 15) * 4;  // out row k0+r, cols h0+c..
    union { _Float16 h[4]; ushort4 u; } cv;
    cv.h[0] = (_Float16)tile[c + 0][r];
    cv.h[1] = (_Float16)tile[c + 1][r];
    cv.h[2] = (_Float16)tile[c + 2][r];
    cv.h[3] = (_Float16)tile[c + 3][r];
    *(ushort4*)(W1T + (size_t)(k0 + r) * HDIM + h0 + c) = cv.u;
  }
}

// ---------------- kernel 2: dec_proj = dh @ W2 + b  (fp32) ----------------
__global__ void k_decproj(const float* __restrict__ dh, const float* __restrict__ W2,
                          const float* __restrict__ W2b, float* __restrict__ dp) {
  __shared__ float drow[HDIM];
  int b = blockIdx.x, t = threadIdx.x;
#pragma unroll
  for (int j = 0; j < 4; ++j) drow[j * 256 + t] = dh[(size_t)b * HDIM + j * 256 + t];
  __syncthreads();
  f32x4 acc = {0.f, 0.f, 0.f, 0.f};
#pragma unroll 16
  for (int h = 0; h < HDIM; ++h) {
    float d = drow[h];
    f32x4 w = *(const f32x4*)(W2 + (size_t)h * HDIM + t * 4);
    acc += w * d;
  }
  acc += *(const f32x4*)(W2b + t * 4);
  *(f32x4*)(dp + (size_t)b * HDIM + t * 4) = acc;
}

// ---------------- kernel 3: main fused GEMM + tanh + v-dot -> score partials ----------------
__global__ __launch_bounds__(256, 2) void k_scores(
    const float* __restrict__ E, const unsigned short* __restrict__ W1T,
    const float* __restrict__ W1b, const float* __restrict__ dp,
    const float* __restrict__ vw, float* __restrict__ spart) {
  __shared__ unsigned short As[BM * BK];   // [row][k] fp16
  __shared__ unsigned short Bs[BN * BK];   // [col][k] fp16 (B^T)
  __shared__ float biasv[BN], vv[BN];
  __shared__ float scr[BM][2];

  int t = threadIdx.x;
  // XCD-aware remap: round-robin dispatch puts bid%8 on XCD (bid&7).
  // Group all 8 n-tiles of one m-tile onto the SAME XCD, adjacent in time,
  // so the 512KB A-panel stays L2-resident and E is HBM-fetched once.
  int bid = blockIdx.x;                 // 0..8191
  int xcd = bid & 7;
  int q = bid >> 3;                     // 0..1023 per XCD
  int mt = (xcd << 7) + (q >> 3);       // 128 m-tiles per XCD
  int nt = q & 7;
  int m0 = mt * BM, n0 = nt * BN;
  int b = m0 >> 11;   // 2048 rows per batch

  if (t < BN) {
    int k = n0 + t;
    biasv[t] = W1b[k] + dp[(size_t)b * HDIM + k];
    vv[t] = vw[k];
  }

  int lane = t & 63, wid = t >> 6;
  int wr = wid >> 1, wc = wid & 1;
  int l15 = lane & 15, l4 = lane >> 4;

  f32x4 acc[4][4];
#pragma unroll
  for (int i = 0; i < 4; ++i)
#pragma unroll
    for (int j = 0; j < 4; ++j) acc[i][j] = {0.f, 0.f, 0.f, 0.f};

  const float* Abase = E + (size_t)m0 * HDIM;

  for (int kt = 0; kt < HDIM / BK; ++kt) {
    // stage A: fp32 -> fp16, reg path
#pragma unroll
    for (int j = 0; j < 4; ++j) {
      int q2 = j * 256 + t;
      int r = q2 >> 3, c = (q2 & 7) * 4;
      float4 v = *(const float4*)(Abase + (size_t)r * HDIM + kt * BK + c);
      union { _Float16 h[4]; unsigned long long u; } cv;
      cv.h[0] = (_Float16)v.x; cv.h[1] = (_Float16)v.y;
      cv.h[2] = (_Float16)v.z; cv.h[3] = (_Float16)v.w;
      *(unsigned long long*)&As[q2 * 4] = cv.u;
    }
    // stage B: fp16 direct global->LDS (linear dest, per-lane src)
#pragma unroll
    for (int j = 0; j < 2; ++j) {
      const unsigned short* g = W1T + (size_t)(n0 + (wid * 2 + j) * 16) * HDIM
                              + (size_t)(lane >> 2) * HDIM   // row within 16-row group
                              + kt * BK + (lane & 3) * 8;    // 8 fp16 = 16B per lane
      // dest must be linear in lane order: lane i -> bytes [i*16, i*16+16)
      gload_lds16(g, (char*)Bs + (size_t)(wid * 2 + j) * 1024);
    }
    __syncthreads();

    half8 af[4], bf[4];
#pragma unroll
    for (int mi = 0; mi < 4; ++mi)
      af[mi] = *(const half8*)&As[(wr * 64 + mi * 16 + l15) * BK + l4 * 8];
#pragma unroll
    for (int ni = 0; ni < 4; ++ni)
      bf[ni] = *(const half8*)&Bs[(wc * 64 + ni * 16 + l15) * BK + l4 * 8];
#pragma unroll
    for (int mi = 0; mi < 4; ++mi)
#pragma unroll
      for (int ni = 0; ni < 4; ++ni)
        acc[mi][ni] = __builtin_amdgcn_mfma_f32_16x16x32_f16(af[mi], bf[ni], acc[mi][ni], 0, 0, 0);
    __syncthreads();
  }

  // epilogue: bias + tanh + v-dot, reduce 16 cols/lane-group, then across wc via LDS
  float bias_l[4], v_l[4];
#pragma unroll
  for (int ni = 0; ni < 4; ++ni) {
    bias_l[ni] = biasv[wc * 64 + ni * 16 + l15];
    v_l[ni] = vv[wc * 64 + ni * 16 + l15];
  }
#pragma unroll
  for (int mi = 0; mi < 4; ++mi) {
#pragma unroll
    for (int r = 0; r < 4; ++r) {
      float s = 0.f;
#pragma unroll
      for (int ni = 0; ni < 4; ++ni) {
        float x = acc[mi][ni][r] + bias_l[ni];
        float ex = __expf(2.f * x);
        float th = 1.f - 2.f / (ex + 1.f);   // tanh(x), saturates correctly at +-1
        s += th * v_l[ni];
      }
      s += __shfl_xor(s, 1); s += __shfl_xor(s, 2);
      s += __shfl_xor(s, 4); s += __shfl_xor(s, 8);
      if (l15 == 0) scr[wr * 64 + mi * 16 + l4 * 4 + r][wc] = s;
    }
  }
  __syncthreads();
  if (t < BM) spart[((size_t)m0 + t) * 8 + nt] = scr[t][0] + scr[t][1];
}

// ---------------- kernel 4: softmax over S per batch ----------------
__global__ void k_softmax(const float* __restrict__ spart, float* __restrict__ attn) {
  __shared__ float sc[SEQ];
  __shared__ float red[8];
  int b = blockIdx.x, t = threadIdx.x;
  float mx = -1e30f;
#pragma unroll
  for (int j = 0; j < 8; ++j) {
    int s = j * 256 + t;
    const f32x4* p = (const f32x4*)(spart + ((size_t)b * SEQ + s) * 8);
    f32x4 x = p[0], y = p[1];
    float v = (x[0] + x[1]) + (x[2] + x[3]) + (y[0] + y[1]) + (y[2] + y[3]);
    sc[s] = v;
    mx = fmaxf(mx, v);
  }
  for (int m = 1; m < 64; m <<= 1) mx = fmaxf(mx, __shfl_xor(mx, m));
  if ((t & 63) == 0) red[t >> 6] = mx;
  __syncthreads();
  mx = fmaxf(fmaxf(red[0], red[1]), fmaxf(red[2], red[3]));
  float w[8]; float sum = 0.f;
#pragma unroll
  for (int j = 0; j < 8; ++j) {
    float e = __expf(sc[j * 256 + t] - mx);
    w[j] = e; sum += e;
  }
  for (int m = 1; m < 64; m <<= 1) sum += __shfl_xor(sum, m);
  if ((t & 63) == 0) red[4 + (t >> 6)] = sum;
  __syncthreads();
  float inv = 1.f / (red[4] + red[5] + red[6] + red[7]);
#pragma unroll
  for (int j = 0; j < 8; ++j)
    attn[(size_t)b * SEQ + j * 256 + t] = w[j] * inv;
}

// ---------------- kernel 5: context partials over s-chunks ----------------
__global__ void k_ctx_part(const float* __restrict__ E, const float* __restrict__ attn,
                           float* __restrict__ cpart) {
  int b = blockIdx.x >> 4, ch = blockIdx.x & 15;
  int t = threadIdx.x;
  const float* wrow = attn + (size_t)b * SEQ + ch * 128;
  const float* Eb = E + ((size_t)b * SEQ + ch * 128) * HDIM;
  f32x4 acc = {0.f, 0.f, 0.f, 0.f};
#pragma unroll 4
  for (int s = 0; s < 128; ++s) {
    float w = wrow[s];
    f32x4 e = *(const f32x4*)(Eb + (size_t)s * HDIM + t * 4);
    acc += e * w;
  }
  *(f32x4*)(cpart + (size_t)blockIdx.x * HDIM + t * 4) = acc;
}

// ---------------- kernel 6: reduce context partials ----------------
__global__ void k_ctx_reduce(const float* __restrict__ cpart, float* __restrict__ ctx) {
  int idx = blockIdx.x * 256 + threadIdx.x;  // 0..65535
  int b = idx >> 10, k = idx & 1023;
  float s = 0.f;
#pragma unroll
  for (int c = 0; c < 16; ++c) s += cpart[((size_t)(b * 16 + c)) * HDIM + k];
  ctx[idx] = s;
}

extern "C" void kernel_launch(void* const* d_in, const int* in_sizes, int n_in,
                              void* d_out, int out_size, void* d_ws, size_t ws_size,
                              hipStream_t stream) {
  const float* dh  = (const float*)d_in[0];
  const float* E   = (const float*)d_in[1];
  const float* W1w = (const float*)d_in[2];
  const float* W1b = (const float*)d_in[3];
  const float* W2w = (const float*)d_in[4];
  const float* W2b = (const float*)d_in[5];
  const float* vw  = (const float*)d_in[6];
  float* out  = (float*)d_out;
  float* ctx  = out;            // [64,1024]
  float* attn = out + BATCH * HDIM;  // [64,2048]

  char* ws = (char*)d_ws;
  unsigned short* W1T = (unsigned short*)ws;                       // 2 MB
  float* dp    = (float*)(ws + (2u << 20));                        // 256 KB
  float* spart = (float*)(ws + (2u << 20) + (256u << 10));         // 4 MB
  float* cpart = (float*)(ws + (6u << 20) + (256u << 10));         // 4 MB
  // total ws use: 10.25 MB

  k_w1t<<<dim3(16, 16), 256, 0, stream>>>(W1w, W1T);
  k_decproj<<<BATCH, 256, 0, stream>>>(dh, W2w, W2b, dp);
  k_scores<<<(MTOT / BM) * (HDIM / BN), 256, 0, stream>>>(E, W1T, W1b, dp, vw, spart);
  k_softmax<<<BATCH, 256, 0, stream>>>(spart, attn);
  k_ctx_part<<<BATCH * 16, 256, 0, stream>>>(E, attn, cpart);
  k_ctx_reduce<<<256, 256, 0, stream>>>(cpart, ctx);
}